// Round 26
// baseline (116.282 us; speedup 1.0000x reference)
//
#include <hip/hip_runtime.h>

#define DEVI __device__ __forceinline__

typedef __attribute__((ext_vector_type(8)))  short bh8;   // 8 x bf16 MFMA A/B frag
typedef __attribute__((ext_vector_type(4)))  float fx4;
typedef __attribute__((ext_vector_type(16))) float fx16;  // 32x32 MFMA C/D frag

DEVI unsigned short f2b(float f){            // fp32 -> bf16, RNE
  unsigned u = __float_as_uint(f);
  u += 0x7FFFu + ((u >> 16) & 1u);
  return (unsigned short)(u >> 16);
}
DEVI float b2f(unsigned short b){ return __uint_as_float(((unsigned)b) << 16); }

DEVI unsigned cvtpk(float a, float b){       // pack 2 f32 -> 2 bf16 (RNE), 1 inst
  unsigned r;
  asm("v_cvt_pk_bf16_f32 %0, %1, %2" : "=v"(r) : "v"(a), "v"(b));
  return r;
}
DEVI float fexp2(float x){                   // raw v_exp_f32 (2^x), no OCML guards
  float r;
  asm("v_exp_f32 %0, %1" : "=v"(r) : "v"(x));
  return r;
}

typedef __attribute__((address_space(1))) const void gvoid;
typedef __attribute__((address_space(3))) void svoid;
DEVI void gload16(const void* g, void* l){
  __builtin_amdgcn_global_load_lds((gvoid*)g, (svoid*)l, 16, 0, 0);
}

union pfu { unsigned u[4]; bh8 v; };

// ------------------------------- fused cast x3 (grid-stride, G11) + rope table
__global__ __launch_bounds__(256) void cast3_kernel(
    const float* __restrict__ x, const float* __restrict__ w1f, const float* __restrict__ w2f,
    unsigned short* __restrict__ x16, unsigned short* __restrict__ w1, unsigned short* __restrict__ w2,
    float* __restrict__ ct, float* __restrict__ st)
{
  if (blockIdx.x >= 2048){
    int i = (blockIdx.x - 2048) * 256 + threadIdx.x;   // 32768 entries
    int pos = i >> 5, j = i & 31;
    float freq = __expf(-(float)j * 0.28782313662425576f);  // ln(10000)/32
    float sv, cv; sincosf((float)pos * freq, &sv, &cv);
    ct[i] = cv; st[i] = sv;
    return;
  }
  for (int i = blockIdx.x * 256 + threadIdx.x; i < 2097152; i += 524288){
    const float* src; unsigned short* dst; int off;
    if (i < 1048576)      { src = x;   dst = x16; off = i; }
    else if (i < 1835008) { src = w1f; dst = w1;  off = i - 1048576; }
    else                  { src = w2f; dst = w2;  off = i - 1835008; }
    float4 v = ((const float4*)src)[off];
    short4 r;
    r.x = (short)f2b(v.x); r.y = (short)f2b(v.y);
    r.z = (short)f2b(v.z); r.w = (short)f2b(v.w);
    ((short4*)dst)[off] = r;
  }
}

#define QSCALE 0.18033688011112042f

// --------------------- 128x128 QKV GEMM + FUSED LayerNorm/RoPE/V-transpose
// R25 form: 512 threads / 8 waves (4Mx2N of 32x64), 3-stage LDS, vmcnt(2).
template<int XW, int GM>
__global__ __launch_bounds__(512) void gemm_qkv(
    const unsigned short* __restrict__ A, const unsigned short* __restrict__ B,
    const float* __restrict__ qnw, const float* __restrict__ qnb,
    const float* __restrict__ knw, const float* __restrict__ knb,
    const float* __restrict__ ct, const float* __restrict__ st,
    unsigned short* __restrict__ qo, unsigned short* __restrict__ ko,
    unsigned short* __restrict__ vt, int N, int K)
{
  __shared__ char sm[49152];  // 3 x (A[128][32] 8KB + B[128][32] 8KB)
  const int t = threadIdx.x, wv = t >> 6, ln = t & 63, lr = ln & 15, lg = ln >> 4;
  const int orig = blockIdx.y * gridDim.x + blockIdx.x;
  const int xcd = orig & 7, idx = orig >> 3;
  const int GN = (gridDim.x * XW) >> 3;
  const int bm = ((xcd % XW) * GM + (idx % GM)) << 7;
  const int bn = ((xcd / XW) * GN + (idx / GM)) << 7;
  const int wr = wv >> 1, wc = wv & 1;   // 4x2 waves; sub-tile 32(M)x64(N)
  const fx4 fz = {0.f, 0.f, 0.f, 0.f};
  fx4 acc[2][4];
#pragma unroll
  for (int i = 0; i < 2; i++)
#pragma unroll
    for (int j = 0; j < 4; j++) acc[i][j] = fz;
  const int kiters = K >> 5;

// 512 threads: 1 A-chunk + 1 B-chunk (16B) each; LDS linear addr = t*16 B.
#define GSTAGE(dst, k0) do{                                                       \
    int row_ = t >> 2, col_ = (t & 3) << 3;                                       \
    gload16(A + (size_t)(bm + row_)*K + (k0) + col_, (dst) + wv*1024);            \
    gload16(B + (size_t)(bn + row_)*K + (k0) + col_, (dst) + 8192 + wv*1024);     \
  }while(0)

  char* p0 = sm; char* p1 = sm + 16384; char* p2 = sm + 32768;
  GSTAGE(p0, 0);
  GSTAGE(p1, 32);
  asm volatile("s_waitcnt vmcnt(0)" ::: "memory");   // prologue: full drain (R12 rule)
  __builtin_amdgcn_s_barrier();
  __builtin_amdgcn_sched_barrier(0);

  for (int ki = 0; ki < kiters; ++ki){
    if (ki + 2 < kiters) GSTAGE(p2, (ki + 2) << 5);
    bh8 af[2], bf[4];
#pragma unroll
    for (int mi = 0; mi < 2; mi++)
      af[mi] = *(const bh8*)(p0 + (wr*32 + mi*16 + lr)*64 + lg*16);
#pragma unroll
    for (int ni = 0; ni < 4; ni++)
      bf[ni] = *(const bh8*)(p0 + 8192 + (wc*64 + ni*16 + lr)*64 + lg*16);
    __builtin_amdgcn_s_setprio(1);
#pragma unroll
    for (int mi = 0; mi < 2; mi++)
#pragma unroll
      for (int ni = 0; ni < 4; ni++)
        acc[mi][ni] = __builtin_amdgcn_mfma_f32_16x16x32_bf16(af[mi], bf[ni], acc[mi][ni], 0, 0, 0);
    __builtin_amdgcn_s_setprio(0);
    if (ki + 2 < kiters) asm volatile("s_waitcnt vmcnt(2) lgkmcnt(0)" ::: "memory");
    else                 asm volatile("s_waitcnt vmcnt(0) lgkmcnt(0)" ::: "memory");
    __builtin_amdgcn_s_barrier();
    __builtin_amdgcn_sched_barrier(0);
    char* tmp = p0; p0 = p1; p1 = p2; p2 = tmp;
  }
#undef GSTAGE

  // ---------------- fused epilogue (R15 form; 32 tokens/wave) ----------------
  const int col0 = bn + wc*64;          // 64-aligned -> one (which, head)
  const int which = col0 >> 10;         // 0=q, 1=k, 2=v
  const int h = (col0 >> 6) & 15;
  const int rowbase = bm + wr*32;
  if (which == 2){
#pragma unroll
    for (int mi = 0; mi < 2; mi++)
#pragma unroll
      for (int ni = 0; ni < 4; ni++){
        int row = rowbase + mi*16 + lg*4;
        int b = row >> 11, n = row & 2047;
        size_t vb = (((size_t)(b*16 + h))*64 + ni*16 + lr)*2048 + n;
        short4 pk;
        pk.x = (short)f2b(acc[mi][ni][0]);
        pk.y = (short)f2b(acc[mi][ni][1]);
        pk.z = (short)f2b(acc[mi][ni][2]);
        pk.w = (short)f2b(acc[mi][ni][3]);
        *(short4*)&vt[vb] = pk;
      }
  } else {
    const float* gw = which ? knw : qnw;
    const float* gb = which ? knb : qnb;
    const float w0 = gw[lr], w1_ = gw[16+lr], w2_ = gw[32+lr], w3 = gw[48+lr];
    const float b0 = gb[lr], b1_ = gb[16+lr], b2_ = gb[32+lr], b3 = gb[48+lr];
    const float qs = which ? 1.0f : QSCALE;
    unsigned short* dst = which ? ko : qo;
#pragma unroll
    for (int mi = 0; mi < 2; mi++)
#pragma unroll
      for (int r = 0; r < 4; r++){
        float x0 = acc[mi][0][r], x1 = acc[mi][1][r];
        float x2 = acc[mi][2][r], x3 = acc[mi][3][r];
        float s  = (x0 + x1) + (x2 + x3);
        float q2 = (x0*x0 + x1*x1) + (x2*x2 + x3*x3);
#pragma unroll
        for (int off = 1; off < 16; off <<= 1){
          s  += __shfl_xor(s,  off);
          q2 += __shfl_xor(q2, off);
        }
        float mean = s * (1.f/64.f);
        float rstd = rsqrtf(q2*(1.f/64.f) - mean*mean + 1e-5f);
        float y0 = (x0-mean)*rstd*w0 + b0, y1 = (x1-mean)*rstd*w1_ + b1_;
        float y2 = (x2-mean)*rstd*w2_ + b2_, y3 = (x3-mean)*rstd*w3 + b3;
        int row = rowbase + mi*16 + lg*4 + r;
        int b = row >> 11, n = row & 2047, pos = row & 1023;  // pos restarts at n/2
        float c0 = ct[pos*32 + lr],      s0 = st[pos*32 + lr];
        float c1 = ct[pos*32 + 16 + lr], s1 = st[pos*32 + 16 + lr];
        float o0 = (y0*c0 - y2*s0) * qs;   // d = lr
        float o1 = (y1*c1 - y3*s1) * qs;   // d = 16+lr
        float o2 = (y2*c0 + y0*s0) * qs;   // d = 32+lr
        float o3 = (y3*c1 + y1*s1) * qs;   // d = 48+lr
        size_t ob = (((size_t)(b*16 + h))*2048 + n)*64;
        dst[ob + lr]      = f2b(o0);
        dst[ob + 16 + lr] = f2b(o1);
        dst[ob + 32 + lr] = f2b(o2);
        dst[ob + 48 + lr] = f2b(o3);
      }
  }
}

// ------------------------------------------- bf16 GEMM 64x64 (proj, R26)
// 1024 blocks = 4/CU x 8 waves = 32 waves/CU (HW max). 8 waves as 4Mx2N of
// 16x32 sub-tiles (acc[1][2]). Staging: 8KB/stage, EXACTLY 1 gload/thread
// (waves 0-3 stage A, 4-7 stage B; LDS dest = dst + wv*1024). 3-stage,
// steady vmcnt(1); prologue full-drain (R12 rule). K-chain identical.
__global__ __launch_bounds__(512) void gemm_bt64(
    const unsigned short* __restrict__ A, const unsigned short* __restrict__ B,
    float* __restrict__ Cf, const float* __restrict__ bias, int M, int N, int K)
{
  __shared__ char sm[24576];  // 3 x (A[64][32] 4KB + B[64][32] 4KB)
  const int t = threadIdx.x, wv = t >> 6, ln = t & 63, lr = ln & 15, lg = ln >> 4;
  const int orig = blockIdx.y * gridDim.x + blockIdx.x;   // grid (16,64) = 1024
  const int xcd = orig & 7, idx = orig >> 3;              // idx in [0,128)
  const int bm = (((xcd & 3) << 4) + (idx & 15)) << 6;    // 64 m-tiles, bijective
  const int bn = (((xcd >> 2) << 3) + (idx >> 4)) << 6;   // 16 n-tiles
  const int wr = wv >> 1, wc = wv & 1;   // 4x2 waves; sub-tile 16(M)x32(N)
  const fx4 fz = {0.f, 0.f, 0.f, 0.f};
  fx4 acc[2];
  acc[0] = fz; acc[1] = fz;
  const int kiters = K >> 5;

// 512 threads, 1 chunk each: t<256 -> A chunk t, t>=256 -> B chunk t-256.
// chunk c: row = c>>2, col = (c&3)*8. LDS: A at [0,4K), B at [4K,8K).
#define GSTAGE(dst, k0) do{                                                       \
    int c_ = t & 255;                                                             \
    int row_ = c_ >> 2, col_ = (c_ & 3) << 3;                                     \
    const unsigned short* g_ = (t < 256)                                          \
        ? A + (size_t)(bm + row_)*K + (k0) + col_                                 \
        : B + (size_t)(bn + row_)*K + (k0) + col_;                                \
    gload16(g_, (dst) + wv*1024);                                                 \
  }while(0)

  char* p0 = sm; char* p1 = sm + 8192; char* p2 = sm + 16384;
  GSTAGE(p0, 0);
  GSTAGE(p1, 32);
  asm volatile("s_waitcnt vmcnt(0)" ::: "memory");   // prologue: full drain (R12 rule)
  __builtin_amdgcn_s_barrier();
  __builtin_amdgcn_sched_barrier(0);

  for (int ki = 0; ki < kiters; ++ki){
    if (ki + 2 < kiters) GSTAGE(p2, (ki + 2) << 5);
    bh8 af, bf[2];
    af = *(const bh8*)(p0 + (wr*16 + lr)*64 + lg*16);
#pragma unroll
    for (int ni = 0; ni < 2; ni++)
      bf[ni] = *(const bh8*)(p0 + 4096 + (wc*32 + ni*16 + lr)*64 + lg*16);
    __builtin_amdgcn_s_setprio(1);
#pragma unroll
    for (int ni = 0; ni < 2; ni++)
      acc[ni] = __builtin_amdgcn_mfma_f32_16x16x32_bf16(af, bf[ni], acc[ni], 0, 0, 0);
    __builtin_amdgcn_s_setprio(0);
    if (ki + 2 < kiters) asm volatile("s_waitcnt vmcnt(1) lgkmcnt(0)" ::: "memory");
    else                 asm volatile("s_waitcnt vmcnt(0) lgkmcnt(0)" ::: "memory");
    __builtin_amdgcn_s_barrier();
    __builtin_amdgcn_sched_barrier(0);
    char* tmp = p0; p0 = p1; p1 = p2; p2 = tmp;
  }
#undef GSTAGE
#pragma unroll
  for (int ni = 0; ni < 2; ni++){
    int col = bn + wc*32 + ni*16 + lr;
#pragma unroll
    for (int r = 0; r < 4; r++){
      int row = bm + wr*16 + lg*4 + r;
      Cf[(size_t)row * N + col] = acc[ni][r] + bias[col];
    }
  }
}

// ------------------------------------------------------------ flash attention
// R20 form: 2-stage LDS, 4 blocks/CU, fixed-max softmax (known-good best).
__global__ __launch_bounds__(512, 4) void attn_kernel(
    const unsigned short* __restrict__ qg, const unsigned short* __restrict__ kg,
    const unsigned short* __restrict__ vg, unsigned short* __restrict__ og)
{
  __shared__ char sm[34048];   // 2 x (K 8KB + V 8KB) + f32 combine pad
  const int t = threadIdx.x, wv = t >> 6, ln = t & 63, lq = ln & 31, hi = ln >> 5;
  const int kvh = wv >> 2;     // kv half this wave reduces
  const int wq  = wv & 3;      // q sub-block (32 rows each)
  const int swz = ((blockIdx.x & 7) << 6) | (blockIdx.x >> 3);
  const int bh = swz >> 4, q0 = (swz & 15) << 7;
  const unsigned short* kbase = kg + ((size_t)bh << 17);
  const unsigned short* vbase = vg + ((size_t)bh << 17);
  const size_t qrow = ((size_t)bh << 11) + q0 + wq*32 + lq;
  bh8 qf[4];
#pragma unroll
  for (int s2 = 0; s2 < 4; s2++) qf[s2] = *(const bh8*)&qg[qrow*64 + s2*16 + hi*8];

  fx16 o0, o1;
#pragma unroll
  for (int i = 0; i < 16; i++){ o0[i] = 0.f; o1[i] = 0.f; }
  float l_r = 0.f;
  const bool qfirst = (q0 < 1024);
  const int swsl = lq & 7;

// 512 threads: each stages 1 K-chunk + 1 V-chunk (16B each) per tile
#define STAGE(dst, kt) do{                                                        \
    int row_ = t >> 3, sl_ = (t & 7) ^ (row_ & 7);                                \
    gload16(kbase + (size_t)((kt) + row_)*64 + sl_*8, (dst) + wv*1024);           \
    gload16(vbase + (size_t)row_*2048 + (kt) + sl_*8, (dst) + 8192 + wv*1024);    \
  }while(0)

  char* cur = sm; char* oth = sm + 16384;
  STAGE(cur, 0);
  // FULL drain at prologue (reorder-safe, R12 rule)
  asm volatile("s_waitcnt vmcnt(0)" ::: "memory");
  __builtin_amdgcn_s_barrier();
  __builtin_amdgcn_sched_barrier(0);

  for (int tile = 0; tile < 32; ++tile){
    if (tile < 31) STAGE(oth, (tile + 1)*64);
    const char* Kc = cur;
    const char* Vc = cur + 8192;
    // ---- S^T = K(half) · Q^T ; bias folded into C-init (log2(0.5) = -1)
    const float bias2 = (qfirst != (tile < 16)) ? -1.0f : 0.0f;
    fx16 sA;
#pragma unroll
    for (int i = 0; i < 16; i++) sA[i] = bias2;
    __builtin_amdgcn_s_setprio(1);
#pragma unroll
    for (int s2 = 0; s2 < 4; s2++){
      const int slot = s2*2 + hi;
      bh8 kf = *(const bh8*)(Kc + (kvh*32 + lq)*128 + ((slot ^ swsl) << 4));
      sA = __builtin_amdgcn_mfma_f32_32x32x16_bf16(kf, qf[s2], sA, 0, 0, 0);
    }
    __builtin_amdgcn_s_setprio(0);
    // ---- V fragments early (latency under softmax); kv cols = this wave's half
    bh8 vf0[2], vf1[2];
#pragma unroll
    for (int kg2 = 0; kg2 < 2; kg2++){
      const int slot = kvh*4 + kg2*2 + hi;
      vf0[kg2] = *(const bh8*)(Vc + lq*128      + ((slot ^ swsl) << 4));
      vf1[kg2] = *(const bh8*)(Vc + (32+lq)*128 + ((slot ^ swsl) << 4));
    }
    // ---- fixed-max softmax: p = exp2(s - 16)
    float sum = 0.f;
#pragma unroll
    for (int i = 0; i < 16; i++){
      sA[i] = fexp2(sA[i] - 16.0f);
      sum += sA[i];
    }
    sum += __shfl_xor(sum, 32);
    l_r += sum;
    // ---- P -> bf16 B-fragments in-register
    bh8 pf[2];
#define MKPF(dst, sv, base) do{                                                   \
    unsigned c0 = cvtpk(sv[base+0], sv[base+1]);                                  \
    unsigned c1 = cvtpk(sv[base+2], sv[base+3]);                                  \
    unsigned c2 = cvtpk(sv[base+4], sv[base+5]);                                  \
    unsigned c3 = cvtpk(sv[base+6], sv[base+7]);                                  \
    asm volatile("v_permlane32_swap_b32 %0, %1" : "+v"(c0), "+v"(c2));            \
    asm volatile("v_permlane32_swap_b32 %0, %1" : "+v"(c1), "+v"(c3));            \
    pfu u_; u_.u[0]=c0; u_.u[1]=c1; u_.u[2]=c2; u_.u[3]=c3; dst = u_.v; }while(0)
    MKPF(pf[0], sA, 0); MKPF(pf[1], sA, 8);
#undef MKPF
    // ---- O^T(partial) += V^T(half) · P^T
    __builtin_amdgcn_s_setprio(1);
#pragma unroll
    for (int kg2 = 0; kg2 < 2; kg2++){
      o0 = __builtin_amdgcn_mfma_f32_32x32x16_bf16(vf0[kg2], pf[kg2], o0, 0, 0, 0);
      o1 = __builtin_amdgcn_mfma_f32_32x32x16_bf16(vf1[kg2], pf[kg2], o1, 0, 0, 0);
    }
    __builtin_amdgcn_s_setprio(0);
    asm volatile("s_waitcnt vmcnt(0) lgkmcnt(0)" ::: "memory");
    __builtin_amdgcn_s_barrier();
    __builtin_amdgcn_sched_barrier(0);
    char* tmp = cur; cur = oth; oth = tmp;
  }
#undef STAGE
  // ---- combine kv halves: waves 4-7 dump (stride 33 f32 = conflict-free),
  //      waves 0-3 add. Fixed-max => plain fp32 adds, l adds too.
  float* fbuf = (float*)sm;
  {
    const int base = (wq*64 + ln)*33;
    if (kvh == 1){
#pragma unroll
      for (int i = 0; i < 16; i++){ fbuf[base+i] = o0[i]; fbuf[base+16+i] = o1[i]; }
      fbuf[base+32] = l_r;
    }
  }
  __syncthreads();
  {
    const int base = (wq*64 + ln)*33;
    if (kvh == 0){
#pragma unroll
      for (int i = 0; i < 16; i++){ o0[i] += fbuf[base+i]; o1[i] += fbuf[base+16+i]; }
      l_r += fbuf[base+32];
    }
  }
  __syncthreads();
  // ---- epilogue (waves 0-3): O^T -> row-major via LDS bounce (stride 132B)
  if (kvh == 0){
    const float inv = 1.0f / l_r;
    const int ql = wq*32 + lq;
#pragma unroll
    for (int j = 0; j < 8; j++){
      int d0 = ((2*j) & 3) + 8*(j >> 1) + 4*hi;
      unsigned w0 = cvtpk(o0[2*j]*inv, o0[2*j+1]*inv);
      unsigned w1 = cvtpk(o1[2*j]*inv, o1[2*j+1]*inv);
      *(unsigned*)(sm + ql*132 + d0*2)        = w0;
      *(unsigned*)(sm + ql*132 + (32 + d0)*2) = w1;
    }
  }
  __syncthreads();
  if (t < 256){
    const int rw = t >> 1, hf = t & 1;
    const int b = bh >> 4, h = bh & 15;
    unsigned short* dst = og + ((size_t)b*2048 + q0 + rw)*1024 + h*64 + hf*32;
#pragma unroll
    for (int u = 0; u < 8; u++){
      short4 v4 = *(short4*)(sm + rw*132 + hf*64 + u*8);
      *(short4*)(dst + u*4) = v4;
    }
  }
}

// ---------------------------------------------------------------- launcher
extern "C" void kernel_launch(void* const* d_in, const int* in_sizes, int n_in,
                              void* d_out, int out_size, void* d_ws, size_t ws_size,
                              hipStream_t stream)
{
  const float* x      = (const float*)d_in[0];
  const float* qkv_w  = (const float*)d_in[1];
  const float* qn_w   = (const float*)d_in[2];
  const float* qn_b   = (const float*)d_in[3];
  const float* kn_w   = (const float*)d_in[4];
  const float* kn_b   = (const float*)d_in[5];
  const float* proj_w = (const float*)d_in[6];
  const float* proj_b = (const float*)d_in[7];
  float* out = (float*)d_out;

  unsigned short* x16   = (unsigned short*)d_ws;          // 4096*1024
  unsigned short* w1    = x16   + (size_t)4096*1024;      // 3072*1024
  unsigned short* w2    = w1    + (size_t)3072*1024;      // 1024*1024
  unsigned short* scr   = w2    + (size_t)1024*1024;      // 24MB scratch
  unsigned short* q16   = scr   + (size_t)4096*3072;      // 2*16*2048*64
  unsigned short* k16   = q16   + (size_t)4194304;
  unsigned short* vt16  = k16   + (size_t)4194304;
  float* ct = (float*)scr;                                // 128KB table
  float* st = ct + 32768;                                 // 128KB table
  unsigned short* o16   = scr + 262144;                   // after tables (8.4MB)

  cast3_kernel<<<2176, 256, 0, stream>>>(x, qkv_w, proj_w, x16, w1, w2, ct, st);
  gemm_qkv<4,8><<<dim3(24, 32), 512, 0, stream>>>(x16, w1, qn_w, qn_b, kn_w, kn_b,
                                                  ct, st, q16, k16, vt16, 3072, 1024);
  attn_kernel<<<512, 512, 0, stream>>>(q16, k16, vt16, o16);
  gemm_bt64<<<dim3(16, 64), 512, 0, stream>>>(o16, w2, out, proj_b, 4096, 1024, 1024);
}

// Round 27
// 112.400 us; speedup vs baseline: 1.0345x; 1.0345x over previous
//
#include <hip/hip_runtime.h>

#define DEVI __device__ __forceinline__

typedef __attribute__((ext_vector_type(8)))  short bh8;   // 8 x bf16 MFMA A/B frag
typedef __attribute__((ext_vector_type(4)))  float fx4;
typedef __attribute__((ext_vector_type(16))) float fx16;  // 32x32 MFMA C/D frag

DEVI unsigned short f2b(float f){            // fp32 -> bf16, RNE
  unsigned u = __float_as_uint(f);
  u += 0x7FFFu + ((u >> 16) & 1u);
  return (unsigned short)(u >> 16);
}
DEVI float b2f(unsigned short b){ return __uint_as_float(((unsigned)b) << 16); }

DEVI unsigned cvtpk(float a, float b){       // pack 2 f32 -> 2 bf16 (RNE), 1 inst
  unsigned r;
  asm("v_cvt_pk_bf16_f32 %0, %1, %2" : "=v"(r) : "v"(a), "v"(b));
  return r;
}
DEVI float fexp2(float x){                   // raw v_exp_f32 (2^x), no OCML guards
  float r;
  asm("v_exp_f32 %0, %1" : "=v"(r) : "v"(x));
  return r;
}

typedef __attribute__((address_space(1))) const void gvoid;
typedef __attribute__((address_space(3))) void svoid;
DEVI void gload16(const void* g, void* l){
  __builtin_amdgcn_global_load_lds((gvoid*)g, (svoid*)l, 16, 0, 0);
}

union pfu { unsigned u[4]; bh8 v; };

// ------------------------------- fused cast x3 (grid-stride, G11) + rope table
__global__ __launch_bounds__(256) void cast3_kernel(
    const float* __restrict__ x, const float* __restrict__ w1f, const float* __restrict__ w2f,
    unsigned short* __restrict__ x16, unsigned short* __restrict__ w1, unsigned short* __restrict__ w2,
    float* __restrict__ ct, float* __restrict__ st)
{
  if (blockIdx.x >= 2048){
    int i = (blockIdx.x - 2048) * 256 + threadIdx.x;   // 32768 entries
    int pos = i >> 5, j = i & 31;
    float freq = __expf(-(float)j * 0.28782313662425576f);  // ln(10000)/32
    float sv, cv; sincosf((float)pos * freq, &sv, &cv);
    ct[i] = cv; st[i] = sv;
    return;
  }
  for (int i = blockIdx.x * 256 + threadIdx.x; i < 2097152; i += 524288){
    const float* src; unsigned short* dst; int off;
    if (i < 1048576)      { src = x;   dst = x16; off = i; }
    else if (i < 1835008) { src = w1f; dst = w1;  off = i - 1048576; }
    else                  { src = w2f; dst = w2;  off = i - 1835008; }
    float4 v = ((const float4*)src)[off];
    short4 r;
    r.x = (short)f2b(v.x); r.y = (short)f2b(v.y);
    r.z = (short)f2b(v.z); r.w = (short)f2b(v.w);
    ((short4*)dst)[off] = r;
  }
}

#define QSCALE 0.18033688011112042f

// --------------------- 128x128 QKV GEMM + FUSED LayerNorm/RoPE/V-transpose
// R25 form: 512 threads / 8 waves (4Mx2N of 32x64), 3-stage LDS, vmcnt(2).
template<int XW, int GM>
__global__ __launch_bounds__(512) void gemm_qkv(
    const unsigned short* __restrict__ A, const unsigned short* __restrict__ B,
    const float* __restrict__ qnw, const float* __restrict__ qnb,
    const float* __restrict__ knw, const float* __restrict__ knb,
    const float* __restrict__ ct, const float* __restrict__ st,
    unsigned short* __restrict__ qo, unsigned short* __restrict__ ko,
    unsigned short* __restrict__ vt, int N, int K)
{
  __shared__ char sm[49152];  // 3 x (A[128][32] 8KB + B[128][32] 8KB)
  const int t = threadIdx.x, wv = t >> 6, ln = t & 63, lr = ln & 15, lg = ln >> 4;
  const int orig = blockIdx.y * gridDim.x + blockIdx.x;
  const int xcd = orig & 7, idx = orig >> 3;
  const int GN = (gridDim.x * XW) >> 3;
  const int bm = ((xcd % XW) * GM + (idx % GM)) << 7;
  const int bn = ((xcd / XW) * GN + (idx / GM)) << 7;
  const int wr = wv >> 1, wc = wv & 1;   // 4x2 waves; sub-tile 32(M)x64(N)
  const fx4 fz = {0.f, 0.f, 0.f, 0.f};
  fx4 acc[2][4];
#pragma unroll
  for (int i = 0; i < 2; i++)
#pragma unroll
    for (int j = 0; j < 4; j++) acc[i][j] = fz;
  const int kiters = K >> 5;

// 512 threads: 1 A-chunk + 1 B-chunk (16B) each; LDS linear addr = t*16 B.
#define GSTAGE(dst, k0) do{                                                       \
    int row_ = t >> 2, col_ = (t & 3) << 3;                                       \
    gload16(A + (size_t)(bm + row_)*K + (k0) + col_, (dst) + wv*1024);            \
    gload16(B + (size_t)(bn + row_)*K + (k0) + col_, (dst) + 8192 + wv*1024);     \
  }while(0)

  char* p0 = sm; char* p1 = sm + 16384; char* p2 = sm + 32768;
  GSTAGE(p0, 0);
  GSTAGE(p1, 32);
  asm volatile("s_waitcnt vmcnt(0)" ::: "memory");   // prologue: full drain (R12 rule)
  __builtin_amdgcn_s_barrier();
  __builtin_amdgcn_sched_barrier(0);

  for (int ki = 0; ki < kiters; ++ki){
    if (ki + 2 < kiters) GSTAGE(p2, (ki + 2) << 5);
    bh8 af[2], bf[4];
#pragma unroll
    for (int mi = 0; mi < 2; mi++)
      af[mi] = *(const bh8*)(p0 + (wr*32 + mi*16 + lr)*64 + lg*16);
#pragma unroll
    for (int ni = 0; ni < 4; ni++)
      bf[ni] = *(const bh8*)(p0 + 8192 + (wc*64 + ni*16 + lr)*64 + lg*16);
    __builtin_amdgcn_s_setprio(1);
#pragma unroll
    for (int mi = 0; mi < 2; mi++)
#pragma unroll
      for (int ni = 0; ni < 4; ni++)
        acc[mi][ni] = __builtin_amdgcn_mfma_f32_16x16x32_bf16(af[mi], bf[ni], acc[mi][ni], 0, 0, 0);
    __builtin_amdgcn_s_setprio(0);
    if (ki + 2 < kiters) asm volatile("s_waitcnt vmcnt(2) lgkmcnt(0)" ::: "memory");
    else                 asm volatile("s_waitcnt vmcnt(0) lgkmcnt(0)" ::: "memory");
    __builtin_amdgcn_s_barrier();
    __builtin_amdgcn_sched_barrier(0);
    char* tmp = p0; p0 = p1; p1 = p2; p2 = tmp;
  }
#undef GSTAGE

  // ---------------- fused epilogue (R15 form; 32 tokens/wave) ----------------
  const int col0 = bn + wc*64;          // 64-aligned -> one (which, head)
  const int which = col0 >> 10;         // 0=q, 1=k, 2=v
  const int h = (col0 >> 6) & 15;
  const int rowbase = bm + wr*32;
  if (which == 2){
#pragma unroll
    for (int mi = 0; mi < 2; mi++)
#pragma unroll
      for (int ni = 0; ni < 4; ni++){
        int row = rowbase + mi*16 + lg*4;
        int b = row >> 11, n = row & 2047;
        size_t vb = (((size_t)(b*16 + h))*64 + ni*16 + lr)*2048 + n;
        short4 pk;
        pk.x = (short)f2b(acc[mi][ni][0]);
        pk.y = (short)f2b(acc[mi][ni][1]);
        pk.z = (short)f2b(acc[mi][ni][2]);
        pk.w = (short)f2b(acc[mi][ni][3]);
        *(short4*)&vt[vb] = pk;
      }
  } else {
    const float* gw = which ? knw : qnw;
    const float* gb = which ? knb : qnb;
    const float w0 = gw[lr], w1_ = gw[16+lr], w2_ = gw[32+lr], w3 = gw[48+lr];
    const float b0 = gb[lr], b1_ = gb[16+lr], b2_ = gb[32+lr], b3 = gb[48+lr];
    const float qs = which ? 1.0f : QSCALE;
    unsigned short* dst = which ? ko : qo;
#pragma unroll
    for (int mi = 0; mi < 2; mi++)
#pragma unroll
      for (int r = 0; r < 4; r++){
        float x0 = acc[mi][0][r], x1 = acc[mi][1][r];
        float x2 = acc[mi][2][r], x3 = acc[mi][3][r];
        float s  = (x0 + x1) + (x2 + x3);
        float q2 = (x0*x0 + x1*x1) + (x2*x2 + x3*x3);
#pragma unroll
        for (int off = 1; off < 16; off <<= 1){
          s  += __shfl_xor(s,  off);
          q2 += __shfl_xor(q2, off);
        }
        float mean = s * (1.f/64.f);
        float rstd = rsqrtf(q2*(1.f/64.f) - mean*mean + 1e-5f);
        float y0 = (x0-mean)*rstd*w0 + b0, y1 = (x1-mean)*rstd*w1_ + b1_;
        float y2 = (x2-mean)*rstd*w2_ + b2_, y3 = (x3-mean)*rstd*w3 + b3;
        int row = rowbase + mi*16 + lg*4 + r;
        int b = row >> 11, n = row & 2047, pos = row & 1023;  // pos restarts at n/2
        float c0 = ct[pos*32 + lr],      s0 = st[pos*32 + lr];
        float c1 = ct[pos*32 + 16 + lr], s1 = st[pos*32 + 16 + lr];
        float o0 = (y0*c0 - y2*s0) * qs;   // d = lr
        float o1 = (y1*c1 - y3*s1) * qs;   // d = 16+lr
        float o2 = (y2*c0 + y0*s0) * qs;   // d = 32+lr
        float o3 = (y3*c1 + y1*s1) * qs;   // d = 48+lr
        size_t ob = (((size_t)(b*16 + h))*2048 + n)*64;
        dst[ob + lr]      = f2b(o0);
        dst[ob + 16 + lr] = f2b(o1);
        dst[ob + 32 + lr] = f2b(o2);
        dst[ob + 48 + lr] = f2b(o3);
      }
  }
}

// ------------------------------------------------- bf16 GEMM 128x128 (proj)
// R24/R25 form: 512 threads / 8 waves (4Mx2N), counted vmcnt(2) (best).
template<int XW, int GM>
__global__ __launch_bounds__(512) void gemm_bt(
    const unsigned short* __restrict__ A, const unsigned short* __restrict__ B,
    float* __restrict__ Cf, const float* __restrict__ bias, int M, int N, int K)
{
  __shared__ char sm[49152];  // 3 x (A[128][32] 8KB + B[128][32] 8KB)
  const int t = threadIdx.x, wv = t >> 6, ln = t & 63, lr = ln & 15, lg = ln >> 4;
  const int orig = blockIdx.y * gridDim.x + blockIdx.x;
  const int xcd = orig & 7, idx = orig >> 3;
  const int GN = (gridDim.x * XW) >> 3;
  const int bm = ((xcd % XW) * GM + (idx % GM)) << 7;
  const int bn = ((xcd / XW) * GN + (idx / GM)) << 7;
  const int wr = wv >> 1, wc = wv & 1;   // 4x2 waves; wave sub-tile 32(M)x64(N)
  const fx4 fz = {0.f, 0.f, 0.f, 0.f};
  fx4 acc[2][4];
#pragma unroll
  for (int i = 0; i < 2; i++)
#pragma unroll
    for (int j = 0; j < 4; j++) acc[i][j] = fz;
  const int kiters = K >> 5;

#define GSTAGE(dst, k0) do{                                                       \
    int row_ = t >> 2, col_ = (t & 3) << 3;                                       \
    gload16(A + (size_t)(bm + row_)*K + (k0) + col_, (dst) + wv*1024);            \
    gload16(B + (size_t)(bn + row_)*K + (k0) + col_, (dst) + 8192 + wv*1024);     \
  }while(0)

  char* p0 = sm; char* p1 = sm + 16384; char* p2 = sm + 32768;
  GSTAGE(p0, 0);
  GSTAGE(p1, 32);
  asm volatile("s_waitcnt vmcnt(0)" ::: "memory");   // prologue: full drain (R12 rule)
  __builtin_amdgcn_s_barrier();
  __builtin_amdgcn_sched_barrier(0);

  for (int ki = 0; ki < kiters; ++ki){
    if (ki + 2 < kiters) GSTAGE(p2, (ki + 2) << 5);
    bh8 af[2], bf[4];
#pragma unroll
    for (int mi = 0; mi < 2; mi++)
      af[mi] = *(const bh8*)(p0 + (wr*32 + mi*16 + lr)*64 + lg*16);
#pragma unroll
    for (int ni = 0; ni < 4; ni++)
      bf[ni] = *(const bh8*)(p0 + 8192 + (wc*64 + ni*16 + lr)*64 + lg*16);
    __builtin_amdgcn_s_setprio(1);
#pragma unroll
    for (int mi = 0; mi < 2; mi++)
#pragma unroll
      for (int ni = 0; ni < 4; ni++)
        acc[mi][ni] = __builtin_amdgcn_mfma_f32_16x16x32_bf16(af[mi], bf[ni], acc[mi][ni], 0, 0, 0);
    __builtin_amdgcn_s_setprio(0);
    if (ki + 2 < kiters) asm volatile("s_waitcnt vmcnt(2) lgkmcnt(0)" ::: "memory");
    else                 asm volatile("s_waitcnt vmcnt(0) lgkmcnt(0)" ::: "memory");
    __builtin_amdgcn_s_barrier();
    __builtin_amdgcn_sched_barrier(0);
    char* tmp = p0; p0 = p1; p1 = p2; p2 = tmp;
  }
#undef GSTAGE
#pragma unroll
  for (int mi = 0; mi < 2; mi++)
#pragma unroll
    for (int ni = 0; ni < 4; ni++){
      int col = bn + wc*64 + ni*16 + lr;
#pragma unroll
      for (int r = 0; r < 4; r++){
        int row = bm + wr*32 + mi*16 + lg*4 + r;
        Cf[(size_t)row * N + col] = acc[mi][ni][r] + bias[col];
      }
    }
}

// ------------------------------------------------------------ flash attention
// R20 form: 2-stage LDS, 4 blocks/CU, fixed-max softmax (known-good best).
__global__ __launch_bounds__(512, 4) void attn_kernel(
    const unsigned short* __restrict__ qg, const unsigned short* __restrict__ kg,
    const unsigned short* __restrict__ vg, unsigned short* __restrict__ og)
{
  __shared__ char sm[34048];   // 2 x (K 8KB + V 8KB) + f32 combine pad
  const int t = threadIdx.x, wv = t >> 6, ln = t & 63, lq = ln & 31, hi = ln >> 5;
  const int kvh = wv >> 2;     // kv half this wave reduces
  const int wq  = wv & 3;      // q sub-block (32 rows each)
  const int swz = ((blockIdx.x & 7) << 6) | (blockIdx.x >> 3);
  const int bh = swz >> 4, q0 = (swz & 15) << 7;
  const unsigned short* kbase = kg + ((size_t)bh << 17);
  const unsigned short* vbase = vg + ((size_t)bh << 17);
  const size_t qrow = ((size_t)bh << 11) + q0 + wq*32 + lq;
  bh8 qf[4];
#pragma unroll
  for (int s2 = 0; s2 < 4; s2++) qf[s2] = *(const bh8*)&qg[qrow*64 + s2*16 + hi*8];

  fx16 o0, o1;
#pragma unroll
  for (int i = 0; i < 16; i++){ o0[i] = 0.f; o1[i] = 0.f; }
  float l_r = 0.f;
  const bool qfirst = (q0 < 1024);
  const int swsl = lq & 7;

// 512 threads: each stages 1 K-chunk + 1 V-chunk (16B each) per tile
#define STAGE(dst, kt) do{                                                        \
    int row_ = t >> 3, sl_ = (t & 7) ^ (row_ & 7);                                \
    gload16(kbase + (size_t)((kt) + row_)*64 + sl_*8, (dst) + wv*1024);           \
    gload16(vbase + (size_t)row_*2048 + (kt) + sl_*8, (dst) + 8192 + wv*1024);    \
  }while(0)

  char* cur = sm; char* oth = sm + 16384;
  STAGE(cur, 0);
  // FULL drain at prologue (reorder-safe, R12 rule)
  asm volatile("s_waitcnt vmcnt(0)" ::: "memory");
  __builtin_amdgcn_s_barrier();
  __builtin_amdgcn_sched_barrier(0);

  for (int tile = 0; tile < 32; ++tile){
    if (tile < 31) STAGE(oth, (tile + 1)*64);
    const char* Kc = cur;
    const char* Vc = cur + 8192;
    // ---- S^T = K(half) · Q^T ; bias folded into C-init (log2(0.5) = -1)
    const float bias2 = (qfirst != (tile < 16)) ? -1.0f : 0.0f;
    fx16 sA;
#pragma unroll
    for (int i = 0; i < 16; i++) sA[i] = bias2;
    __builtin_amdgcn_s_setprio(1);
#pragma unroll
    for (int s2 = 0; s2 < 4; s2++){
      const int slot = s2*2 + hi;
      bh8 kf = *(const bh8*)(Kc + (kvh*32 + lq)*128 + ((slot ^ swsl) << 4));
      sA = __builtin_amdgcn_mfma_f32_32x32x16_bf16(kf, qf[s2], sA, 0, 0, 0);
    }
    __builtin_amdgcn_s_setprio(0);
    // ---- V fragments early (latency under softmax); kv cols = this wave's half
    bh8 vf0[2], vf1[2];
#pragma unroll
    for (int kg2 = 0; kg2 < 2; kg2++){
      const int slot = kvh*4 + kg2*2 + hi;
      vf0[kg2] = *(const bh8*)(Vc + lq*128      + ((slot ^ swsl) << 4));
      vf1[kg2] = *(const bh8*)(Vc + (32+lq)*128 + ((slot ^ swsl) << 4));
    }
    // ---- fixed-max softmax: p = exp2(s - 16)
    float sum = 0.f;
#pragma unroll
    for (int i = 0; i < 16; i++){
      sA[i] = fexp2(sA[i] - 16.0f);
      sum += sA[i];
    }
    sum += __shfl_xor(sum, 32);
    l_r += sum;
    // ---- P -> bf16 B-fragments in-register
    bh8 pf[2];
#define MKPF(dst, sv, base) do{                                                   \
    unsigned c0 = cvtpk(sv[base+0], sv[base+1]);                                  \
    unsigned c1 = cvtpk(sv[base+2], sv[base+3]);                                  \
    unsigned c2 = cvtpk(sv[base+4], sv[base+5]);                                  \
    unsigned c3 = cvtpk(sv[base+6], sv[base+7]);                                  \
    asm volatile("v_permlane32_swap_b32 %0, %1" : "+v"(c0), "+v"(c2));            \
    asm volatile("v_permlane32_swap_b32 %0, %1" : "+v"(c1), "+v"(c3));            \
    pfu u_; u_.u[0]=c0; u_.u[1]=c1; u_.u[2]=c2; u_.u[3]=c3; dst = u_.v; }while(0)
    MKPF(pf[0], sA, 0); MKPF(pf[1], sA, 8);
#undef MKPF
    // ---- O^T(partial) += V^T(half) · P^T
    __builtin_amdgcn_s_setprio(1);
#pragma unroll
    for (int kg2 = 0; kg2 < 2; kg2++){
      o0 = __builtin_amdgcn_mfma_f32_32x32x16_bf16(vf0[kg2], pf[kg2], o0, 0, 0, 0);
      o1 = __builtin_amdgcn_mfma_f32_32x32x16_bf16(vf1[kg2], pf[kg2], o1, 0, 0, 0);
    }
    __builtin_amdgcn_s_setprio(0);
    asm volatile("s_waitcnt vmcnt(0) lgkmcnt(0)" ::: "memory");
    __builtin_amdgcn_s_barrier();
    __builtin_amdgcn_sched_barrier(0);
    char* tmp = cur; cur = oth; oth = tmp;
  }
#undef STAGE
  // ---- combine kv halves: waves 4-7 dump (stride 33 f32 = conflict-free),
  //      waves 0-3 add. Fixed-max => plain fp32 adds, l adds too.
  float* fbuf = (float*)sm;
  {
    const int base = (wq*64 + ln)*33;
    if (kvh == 1){
#pragma unroll
      for (int i = 0; i < 16; i++){ fbuf[base+i] = o0[i]; fbuf[base+16+i] = o1[i]; }
      fbuf[base+32] = l_r;
    }
  }
  __syncthreads();
  {
    const int base = (wq*64 + ln)*33;
    if (kvh == 0){
#pragma unroll
      for (int i = 0; i < 16; i++){ o0[i] += fbuf[base+i]; o1[i] += fbuf[base+16+i]; }
      l_r += fbuf[base+32];
    }
  }
  __syncthreads();
  // ---- epilogue (waves 0-3): O^T -> row-major via LDS bounce (stride 132B)
  if (kvh == 0){
    const float inv = 1.0f / l_r;
    const int ql = wq*32 + lq;
#pragma unroll
    for (int j = 0; j < 8; j++){
      int d0 = ((2*j) & 3) + 8*(j >> 1) + 4*hi;
      unsigned w0 = cvtpk(o0[2*j]*inv, o0[2*j+1]*inv);
      unsigned w1 = cvtpk(o1[2*j]*inv, o1[2*j+1]*inv);
      *(unsigned*)(sm + ql*132 + d0*2)        = w0;
      *(unsigned*)(sm + ql*132 + (32 + d0)*2) = w1;
    }
  }
  __syncthreads();
  if (t < 256){
    const int rw = t >> 1, hf = t & 1;
    const int b = bh >> 4, h = bh & 15;
    unsigned short* dst = og + ((size_t)b*2048 + q0 + rw)*1024 + h*64 + hf*32;
#pragma unroll
    for (int u = 0; u < 8; u++){
      short4 v4 = *(short4*)(sm + rw*132 + hf*64 + u*8);
      *(short4*)(dst + u*4) = v4;
    }
  }
}

// ---------------------------------------------------------------- launcher
extern "C" void kernel_launch(void* const* d_in, const int* in_sizes, int n_in,
                              void* d_out, int out_size, void* d_ws, size_t ws_size,
                              hipStream_t stream)
{
  const float* x      = (const float*)d_in[0];
  const float* qkv_w  = (const float*)d_in[1];
  const float* qn_w   = (const float*)d_in[2];
  const float* qn_b   = (const float*)d_in[3];
  const float* kn_w   = (const float*)d_in[4];
  const float* kn_b   = (const float*)d_in[5];
  const float* proj_w = (const float*)d_in[6];
  const float* proj_b = (const float*)d_in[7];
  float* out = (float*)d_out;

  unsigned short* x16   = (unsigned short*)d_ws;          // 4096*1024
  unsigned short* w1    = x16   + (size_t)4096*1024;      // 3072*1024
  unsigned short* w2    = w1    + (size_t)3072*1024;      // 1024*1024
  unsigned short* scr   = w2    + (size_t)1024*1024;      // 24MB scratch
  unsigned short* q16   = scr   + (size_t)4096*3072;      // 2*16*2048*64
  unsigned short* k16   = q16   + (size_t)4194304;
  unsigned short* vt16  = k16   + (size_t)4194304;
  float* ct = (float*)scr;                                // 128KB table
  float* st = ct + 32768;                                 // 128KB table
  unsigned short* o16   = scr + 262144;                   // after tables (8.4MB)

  cast3_kernel<<<2176, 256, 0, stream>>>(x, qkv_w, proj_w, x16, w1, w2, ct, st);
  gemm_qkv<4,8><<<dim3(24, 32), 512, 0, stream>>>(x16, w1, qn_w, qn_b, kn_w, kn_b,
                                                  ct, st, q16, k16, vt16, 3072, 1024);
  attn_kernel<<<512, 512, 0, stream>>>(q16, k16, vt16, o16);
  gemm_bt<8,4><<<dim3(8, 32), 512, 0, stream>>>(o16, w2, out, proj_b, 4096, 1024, 1024);
}